// Round 1
// baseline (717.265 us; speedup 1.0000x reference)
//
#include <hip/hip_runtime.h>

// Input:  x (16,128,128,128) fp32  -> 2048 planes of 128x128
// Output: y (16,128,256,256) fp32
//
// Derived separable stencil (from reflect-pad(2) + upfirdn2d up=2, k=[1,4,6,4,1]^2/256, gain=4):
//   even out 2j   = 0.5   * (s[refl(j-1)] + s[j])
//   odd  out 2j+1 = 0.125 * (s[refl(j-1)] + 6*s[j] + s[refl(j+1)])
// applied along H then W. refl(-1)=1, refl(128)=126.
//
// This version: 4 input cols per thread (float4 load + __shfl halo),
// YPT=8 rows per thread with register sliding window, float4 nontemporal
// stores (each 32-lane segment writes a full 1KB output row in 2 stores).

constexpr int H = 128, W = 128, OH = 256, OW = 256;
constexpr int TX  = 32;  // threads in x; 4 input cols each
constexpr int BY  = 8;   // threads in y
constexpr int YPT = 8;   // input rows per thread

typedef float f32x4 __attribute__((ext_vector_type(4)));

__global__ __launch_bounds__(256)
void up2x_kernel(const float* __restrict__ x, float* __restrict__ out) {
    const int tx    = threadIdx.x;                                // 0..31
    const int ybase = (blockIdx.y * BY + threadIdx.y) * YPT;      // 0,8,..,120
    const int plane = blockIdx.z;                                 // 0..planes-1

    const float* __restrict__ xin = x + (size_t)plane * (H * W);
    float* __restrict__ o = out + (size_t)plane * (OH * OW);

    // Row state: 6 columns = [left halo, 4 owned cols, right halo]
    float A[6], B[6], C[6];

    auto load_row = [&](const float* __restrict__ row, float* d) {
        const f32x4 v = *reinterpret_cast<const f32x4*>(row + 4 * tx);
        // halo via intra-segment shuffle; reflect edges are the thread's own lanes:
        //   refl(-1)=1  -> col 1   = v.y  (tx==0)
        //   refl(128)=126 -> col 126 = v.z  (tx==31)
        const float lft = __shfl(v.w, tx - 1, TX);
        const float rgt = __shfl(v.x, tx + 1, TX);
        d[0] = (tx == 0)      ? v.y : lft;
        d[1] = v.x; d[2] = v.y; d[3] = v.z; d[4] = v.w;
        d[5] = (tx == TX - 1) ? v.z : rgt;
    };

    // A = row refl(ybase-1), B = row ybase
    load_row(xin + ((ybase == 0) ? 1 : ybase - 1) * W, A);
    load_row(xin + ybase * W, B);

    #pragma unroll
    for (int t = 0; t < YPT; ++t) {
        const int jy = ybase + t;
        // C = row refl(jy+1)
        load_row(xin + ((jy == H - 1) ? H - 2 : jy + 1) * W, C);

        // vertical combine: E feeds even output row 2jy, Q feeds odd row 2jy+1
        float E[6], Q[6];
        #pragma unroll
        for (int c = 0; c < 6; ++c) {
            E[c] = 0.5f   * (A[c] + B[c]);
            Q[c] = 0.125f * (A[c] + 6.0f * B[c] + C[c]);
        }

        // horizontal combine -> 8 output cols (2 per owned input col)
        float to[8], bo[8];
        #pragma unroll
        for (int i = 0; i < 4; ++i) {
            to[2*i]   = 0.5f   * (E[i] + E[i+1]);
            to[2*i+1] = 0.125f * (E[i] + 6.0f * E[i+1] + E[i+2]);
            bo[2*i]   = 0.5f   * (Q[i] + Q[i+1]);
            bo[2*i+1] = 0.125f * (Q[i] + 6.0f * Q[i+1] + Q[i+2]);
        }

        float* r0 = o + (size_t)(2 * jy) * OW + 8 * tx;
        float* r1 = r0 + OW;
        f32x4 s0 = {to[0], to[1], to[2], to[3]};
        f32x4 s1 = {to[4], to[5], to[6], to[7]};
        f32x4 s2 = {bo[0], bo[1], bo[2], bo[3]};
        f32x4 s3 = {bo[4], bo[5], bo[6], bo[7]};
        __builtin_nontemporal_store(s0, reinterpret_cast<f32x4*>(r0));
        __builtin_nontemporal_store(s1, reinterpret_cast<f32x4*>(r0 + 4));
        __builtin_nontemporal_store(s2, reinterpret_cast<f32x4*>(r1));
        __builtin_nontemporal_store(s3, reinterpret_cast<f32x4*>(r1 + 4));

        // slide window down one row
        #pragma unroll
        for (int c = 0; c < 6; ++c) { A[c] = B[c]; B[c] = C[c]; }
    }
}

extern "C" void kernel_launch(void* const* d_in, const int* in_sizes, int n_in,
                              void* d_out, int out_size, void* d_ws, size_t ws_size,
                              hipStream_t stream) {
    const float* x = (const float*)d_in[0];
    float* out = (float*)d_out;
    const int planes = in_sizes[0] / (H * W);  // 16*128 = 2048

    dim3 block(TX, BY, 1);
    dim3 grid(1, H / (BY * YPT), planes);      // (1, 2, 2048)
    up2x_kernel<<<grid, block, 0, stream>>>(x, out);
}

// Round 2
// 601.688 us; speedup vs baseline: 1.1921x; 1.1921x over previous
//
#include <hip/hip_runtime.h>

// Input:  x (16,128,128,128) fp32  -> 2048 planes of 128x128
// Output: y (16,128,256,256) fp32
//
// Derived separable stencil (reflect-pad(2) + upfirdn2d up=2, k=[1,4,6,4,1]^2/256, gain=4):
//   even out 2j   = 0.5   * (s[refl(j-1)] + s[j])
//   odd  out 2j+1 = 0.125 * (s[refl(j-1)] + 6*s[j] + s[refl(j+1)])
// applied along H then W. refl(-1)=1, refl(128)=126.
//
// Layout: one 64-lane wave spans a full input row. Lane i owns input cols
// {2i, 2i+1} (float2 load, 512B/wave contiguous) and produces output cols
// [4i, 4i+4) -> ONE f32x4 NT store per output row = 1KB fully contiguous
// per instruction (fixes round-0's half-filled-line NT stores).
// Halo cols 2i-1 / 2i+2 come from neighbor lanes via __shfl; reflect edges
// resolve to the lane's own .y / .x. YPT=4 rows per thread, register
// sliding window (A,B,C) so each input row is loaded once per thread.

constexpr int H = 128, W = 128, OH = 256, OW = 256;
constexpr int TX  = 64;  // one wave spans a row
constexpr int BY  = 4;   // waves per block
constexpr int YPT = 4;   // input rows per thread

typedef float f32x4 __attribute__((ext_vector_type(4)));

__global__ __launch_bounds__(256)
void up2x_kernel(const float* __restrict__ x, float* __restrict__ out) {
    const int lane  = threadIdx.x;                               // 0..63
    const int ybase = (blockIdx.y * BY + threadIdx.y) * YPT;     // 0,4,..,124
    const int plane = blockIdx.z;                                // 0..planes-1

    const float* __restrict__ xin = x + (size_t)plane * (H * W);
    float* __restrict__ o = out + (size_t)plane * (OH * OW);

    // Row state: [left halo s(2i-1), s(2i), s(2i+1), right halo s(2i+2)]
    float A[4], B[4], C[4];

    auto load_row = [&](const float* __restrict__ row, float* d) {
        const float2 v = *reinterpret_cast<const float2*>(row + 2 * lane);
        const float lft = __shfl(v.y, lane - 1, TX);  // lane i-1's col 2i-1
        const float rgt = __shfl(v.x, lane + 1, TX);  // lane i+1's col 2i+2
        d[0] = (lane == 0)      ? v.y : lft;  // refl(-1) = 1
        d[1] = v.x;
        d[2] = v.y;
        d[3] = (lane == TX - 1) ? v.x : rgt;  // refl(128) = 126
    };

    // A = row refl(ybase-1), B = row ybase
    load_row(xin + ((ybase == 0) ? 1 : ybase - 1) * W, A);
    load_row(xin + ybase * W, B);

    #pragma unroll
    for (int t = 0; t < YPT; ++t) {
        const int jy = ybase + t;
        // C = row refl(jy+1)
        load_row(xin + ((jy == H - 1) ? H - 2 : jy + 1) * W, C);

        // vertical combine: E feeds even output row 2jy, Q feeds odd row 2jy+1
        float E[4], Q[4];
        #pragma unroll
        for (int c = 0; c < 4; ++c) {
            E[c] = 0.5f   * (A[c] + B[c]);
            Q[c] = 0.125f * (A[c] + 6.0f * B[c] + C[c]);
        }

        // horizontal combine -> output cols 4i..4i+3 of rows 2jy, 2jy+1
        f32x4 top, bot;
        top.x = 0.5f   * (E[0] + E[1]);
        top.y = 0.125f * (E[0] + 6.0f * E[1] + E[2]);
        top.z = 0.5f   * (E[1] + E[2]);
        top.w = 0.125f * (E[1] + 6.0f * E[2] + E[3]);
        bot.x = 0.5f   * (Q[0] + Q[1]);
        bot.y = 0.125f * (Q[0] + 6.0f * Q[1] + Q[2]);
        bot.z = 0.5f   * (Q[1] + Q[2]);
        bot.w = 0.125f * (Q[1] + 6.0f * Q[2] + Q[3]);

        float* r0 = o + (size_t)(2 * jy) * OW + 4 * lane;
        __builtin_nontemporal_store(top, reinterpret_cast<f32x4*>(r0));
        __builtin_nontemporal_store(bot, reinterpret_cast<f32x4*>(r0 + OW));

        // slide window down one row
        #pragma unroll
        for (int c = 0; c < 4; ++c) { A[c] = B[c]; B[c] = C[c]; }
    }
}

extern "C" void kernel_launch(void* const* d_in, const int* in_sizes, int n_in,
                              void* d_out, int out_size, void* d_ws, size_t ws_size,
                              hipStream_t stream) {
    const float* x = (const float*)d_in[0];
    float* out = (float*)d_out;
    const int planes = in_sizes[0] / (H * W);  // 16*128 = 2048

    dim3 block(TX, BY, 1);
    dim3 grid(1, H / (BY * YPT), planes);      // (1, 8, 2048)
    up2x_kernel<<<grid, block, 0, stream>>>(x, out);
}